// Round 21
// baseline (163.166 us; speedup 1.0000x reference)
//
#include <hip/hip_runtime.h>
#include <math.h>

// Sizes (fixed): B=16, L=1024, D=50, V=129, d=64, N=2, H=8, DK=8, DFF=128, CVE=8
// LN eps = 1e-14, MASK_ATTN = -1e-30 (~zero!), MASK_POOL = -1e30.

typedef __bf16 bf16x8 __attribute__((ext_vector_type(8)));
typedef __bf16 bf16x2 __attribute__((ext_vector_type(2)));
typedef float f32x16 __attribute__((ext_vector_type(16)));
typedef unsigned int uint4e __attribute__((ext_vector_type(4)));
typedef unsigned long long u64;

static __device__ __forceinline__ float wave_sum64(float x) {
#pragma unroll
    for (int off = 32; off > 0; off >>= 1) x += __shfl_xor(x, off, 64);
    return x;
}

static __device__ __forceinline__ unsigned pack2(float a, float b) {
    bf16x2 t; t[0] = (__bf16)a; t[1] = (__bf16)b;
    return __builtin_bit_cast(unsigned, t);
}

static __device__ __forceinline__ float b2f(__bf16 h) {   // exact bf16 -> f32
    unsigned short us = __builtin_bit_cast(unsigned short, h);
    unsigned u = ((unsigned)us) << 16;
    return __builtin_bit_cast(float, u);
}

static __device__ __forceinline__ float exp2fast(float x) {
#if defined(__has_builtin) && __has_builtin(__builtin_amdgcn_exp2f)
    return __builtin_amdgcn_exp2f(x);
#else
    return exp2f(x);
#endif
}

// lo <- value held by the hi=0 lane of the (lane, lane^32) pair; hi_ <- hi=1 lane's value.
static __device__ __forceinline__ void plswap(unsigned v, unsigned& lo, unsigned& hi_) {
#if defined(__has_builtin) && __has_builtin(__builtin_amdgcn_permlane32_swap)
    auto r = __builtin_amdgcn_permlane32_swap(v, v, false, false);
    lo = r[0]; hi_ = r[1];
#else
    unsigned x = __shfl_xor(v, 32, 64);
    bool h = (threadIdx.x & 32) != 0;
    lo = h ? x : v;
    hi_ = h ? v : x;
#endif
}

// ---------------------------------------------------------------- embeddings + demo (merged)
__global__ __launch_bounds__(256) void embed_demo_kernel(
    const float* __restrict__ times, const float* __restrict__ values,
    const int* __restrict__ varis, const float* __restrict__ emb,
    const float* __restrict__ vW1, const float* __restrict__ vb1, const float* __restrict__ vW2,
    const float* __restrict__ tW1, const float* __restrict__ tb1, const float* __restrict__ tW2,
    const float* __restrict__ demo, const float* __restrict__ dW1, const float* __restrict__ db1,
    const float* __restrict__ dW2, const float* __restrict__ db2,
    float* __restrict__ X, float* __restrict__ mask, float* __restrict__ denc)
{
    __shared__ float sh[128];
    int tid = threadIdx.x;
    if (blockIdx.x < 4096) {
        int row = blockIdx.x * 4 + (tid >> 6);  // (b*L + l)
        int c   = tid & 63;
        float v = values[row];
        float t = times[row];
        int var = varis[row];
        if (c == 0) mask[row] = (var > 0) ? 1.0f : 0.0f;
        float th = 0.f;
        if (c < 8)       th = tanhf(fmaf(v, vW1[c], vb1[c]));
        else if (c < 16) th = tanhf(fmaf(t, tW1[c - 8], tb1[c - 8]));
        float acc = emb[var * 64 + c];
#pragma unroll
        for (int j = 0; j < 8; ++j) {
            acc = fmaf(__shfl(th, j, 64),     vW2[j * 64 + c], acc);
            acc = fmaf(__shfl(th, j + 8, 64), tW2[j * 64 + c], acc);
        }
        X[row * 64 + c] = acc;
    } else {
        int b = blockIdx.x - 4096;
        if (tid < 128) {
            float a = db1[tid];
            for (int j = 0; j < 50; ++j) a = fmaf(demo[b * 50 + j], dW1[j * 128 + tid], a);
            sh[tid] = tanhf(a);
        }
        __syncthreads();
        if (tid < 64) {
            float a2 = db2[tid];
#pragma unroll 8
            for (int j = 0; j < 128; ++j) a2 = fmaf(sh[j], dW2[j * 64 + tid], a2);
            denc[b * 64 + tid] = tanhf(a2);
        }
    }
}

// ---------------------------------------------------------------- qkv projection
__global__ __launch_bounds__(256) void qkv_kernel(
    const float* __restrict__ X, const float* __restrict__ mask,
    const float* __restrict__ Wq, const float* __restrict__ Wk, const float* __restrict__ Wv,
    __bf16* __restrict__ qbf, __bf16* __restrict__ kbf, __bf16* __restrict__ vtb)
{
    __shared__ __align__(16) unsigned char qsm[52224];  // 3 x [64][68] f32
    float* sWq = (float*)qsm;
    float* sWk = sWq + 4352;
    float* sWv = sWk + 4352;
    int tid = threadIdx.x;
    for (int idx = tid; idx < 4096; idx += 256) {
        int h = idx >> 9, c = (idx >> 3) & 63, kk = idx & 7;
        int o = h * 8 + kk;
        sWq[o * 68 + c] = Wq[idx];
        sWk[o * 68 + c] = Wk[idx];
        sWv[o * 68 + c] = Wv[idx];
    }
    int row0 = blockIdx.x * 16;
    __syncthreads();
    int lane = tid & 63;
    int wv4 = (tid >> 6) * 4;                // rows wv4..wv4+3
    float aq[4] = {0.f, 0.f, 0.f, 0.f};
    float ak[4] = {0.f, 0.f, 0.f, 0.f};
    float av[4] = {0.f, 0.f, 0.f, 0.f};
#pragma unroll
    for (int c = 0; c < 64; c += 4) {
        float4 xv[4];
#pragma unroll
        for (int rr = 0; rr < 4; ++rr)
            xv[rr] = *(const float4*)(X + (row0 + wv4 + rr) * 64 + c);  // wave-broadcast
        float4 wq = *(const float4*)(sWq + lane * 68 + c);
        float4 wk = *(const float4*)(sWk + lane * 68 + c);
        float4 wvv= *(const float4*)(sWv + lane * 68 + c);
#pragma unroll
        for (int rr = 0; rr < 4; ++rr) {
            aq[rr] = fmaf(xv[rr].x, wq.x, aq[rr]);  aq[rr] = fmaf(xv[rr].y, wq.y, aq[rr]);
            aq[rr] = fmaf(xv[rr].z, wq.z, aq[rr]);  aq[rr] = fmaf(xv[rr].w, wq.w, aq[rr]);
            ak[rr] = fmaf(xv[rr].x, wk.x, ak[rr]);  ak[rr] = fmaf(xv[rr].y, wk.y, ak[rr]);
            ak[rr] = fmaf(xv[rr].z, wk.z, ak[rr]);  ak[rr] = fmaf(xv[rr].w, wk.w, ak[rr]);
            av[rr] = fmaf(xv[rr].x, wvv.x, av[rr]); av[rr] = fmaf(xv[rr].y, wvv.y, av[rr]);
            av[rr] = fmaf(xv[rr].z, wvv.z, av[rr]); av[rr] = fmaf(xv[rr].w, wvv.w, av[rr]);
        }
    }
    float aqr[4], akr[4], avr[4];
#pragma unroll
    for (int rr = 0; rr < 4; ++rr) {
        float km = mask[row0 + wv4 + rr];   // wave-uniform broadcast
        aqr[rr] = aq[rr] * 1.4426950408889634f;
        akr[rr] = (km != 0.f) ? ak[rr] : 0.f;
        avr[rr] = av[rr];
    }
    __syncthreads();   // weights no longer needed; reuse LDS for repack
    __bf16* sQb = (__bf16*)qsm;
    __bf16* sKb = (__bf16*)(qsm + 2304);
    __bf16* sVt = (__bf16*)(qsm + 4608);   // [64][18]
    int h = lane >> 3, kk = lane & 7;
#pragma unroll
    for (int rr = 0; rr < 4; ++rr) {
        int r = wv4 + rr;
        sQb[h * 136 + r * 8 + kk] = (__bf16)aqr[rr];
        sKb[h * 136 + r * 8 + kk] = (__bf16)akr[rr];
        sVt[lane * 18 + r] = (__bf16)avr[rr];
    }
    __syncthreads();
    int b = row0 >> 10, l0 = row0 & 1023;
    unsigned* qg = (unsigned*)qbf;
    unsigned* kg = (unsigned*)kbf;
    const unsigned* q32 = (const unsigned*)sQb;
    const unsigned* k32 = (const unsigned*)sKb;
#pragma unroll
    for (int it = 0; it < 2; ++it) {
        int idx = it * 256 + tid;            // 0..511
        int hh = idx >> 6, w = idx & 63;     // per h: 64 u32 = 256B dense
        int gbase = ((b * 8 + hh) * 1024 + l0) * 4;
        qg[gbase + w] = q32[hh * 68 + w];
        kg[gbase + w] = k32[hh * 68 + w];
    }
#pragma unroll
    for (int it = 0; it < 2; ++it) {
        int idx = it * 256 + tid;            // 0..511 -> (hkk, lpair)
        int hkk = idx >> 3, lp = idx & 7;
        unsigned w = ((const unsigned*)sVt)[hkk * 9 + lp];
        int hh = hkk >> 3, k2 = hkk & 7;
        ((unsigned*)(vtb + (b * 8 + hh) * 8192 + k2 * 1024 + l0))[lp] = w;
    }
}

// ---------------------------------------------------------------- MFMA attention (NO split-K)
// ONE q-group per wave (~60 live VGPRs, no spill). Grid 1024 = 8 chunks x 128 bh.
__global__ __launch_bounds__(256, 2) void attn_mfma_kernel(
    const __bf16* __restrict__ qbf, const __bf16* __restrict__ kbf,
    const __bf16* __restrict__ vtb, float* __restrict__ O)
{
    __shared__ __align__(16) unsigned char smem[35008];
    __bf16* sK  = (__bf16*)smem;             // [1024 keys][8] = 16384B
    __bf16* sVT = (__bf16*)(smem + 16384);   // rows 0..7 V^T (stride 1032), row 8 ones

    int tid   = threadIdx.x;
    int bh    = blockIdx.x & 127;
    int chunk = blockIdx.x >> 7;             // 0..7

    const u64* kg = (const u64*)(kbf + bh * 8192);
    u64* sKq = (u64*)sK;
#pragma unroll
    for (int i = 0; i < 8; ++i) sKq[i * 256 + tid] = kg[i * 256 + tid];

    const u64* vgb = (const u64*)(vtb + bh * 8192);
#pragma unroll
    for (int it = 0; it < 8; ++it) {
        int idx = it * 256 + tid;
        int r = idx >> 8, w = idx & 255;
        ((u64*)(sVT + r * 1032))[w] = vgb[idx];
    }
    {
        unsigned* p1 = (unsigned*)(sVT + 8 * 1032);
        p1[tid] = 0x3f803f80u;
        p1[256 + tid] = 0x3f803f80u;
    }
    __syncthreads();

    int lane = tid & 63;
    int wv   = tid >> 6;
    int hi   = lane >> 5;
    int l31  = lane & 31;
    unsigned hm = hi ? 0u : 0xffffffffu;

    int qrow = chunk * 128 + wv * 32 + l31;

    bf16x8 qf;
    {
        const __bf16* qp = qbf + (bh * 1024 + qrow) * 8;
        uint4e qa = *(const uint4e*)qp;
        qa[0] &= hm; qa[1] &= hm; qa[2] &= hm; qa[3] &= hm;
        qf = __builtin_bit_cast(bf16x8, qa);
    }

    f32x16 acc, zc;
#pragma unroll
    for (int i = 0; i < 16; ++i) { acc[i] = 0.f; zc[i] = 0.f; }

    const bf16x8* sKv = (const bf16x8*)sK;
    const __bf16* vbase = sVT + (l31 < 8 ? l31 : 8) * 1032;

    bf16x8 kf = sKv[l31];
#pragma unroll 2
    for (int kt = 0; kt < 32; ++kt) {
        bf16x8 kfn = sKv[((kt + 1) & 31) * 32 + l31];
        f32x16 st = __builtin_amdgcn_mfma_f32_32x32x16_bf16(kf, qf, zc, 0, 0, 0);
        float p[16];
#pragma unroll
        for (int r = 0; r < 16; ++r) p[r] = exp2fast(st[r]);

#pragma unroll
        for (int h = 0; h < 2; ++h) {
            unsigned La0, Ha0, Lb0, Hb0, La1, Ha1, Lb1, Hb1;
            int g0 = 2 * h, g1 = 2 * h + 1;
            plswap(pack2(p[4 * g0 + 0], p[4 * g0 + 1]), La0, Ha0);
            plswap(pack2(p[4 * g0 + 2], p[4 * g0 + 3]), Lb0, Hb0);
            plswap(pack2(p[4 * g1 + 0], p[4 * g1 + 1]), La1, Ha1);
            plswap(pack2(p[4 * g1 + 2], p[4 * g1 + 3]), Lb1, Hb1);
            uint4e pw;
            pw[0] = hi ? La1 : La0;
            pw[1] = hi ? Lb1 : Lb0;
            pw[2] = hi ? Ha1 : Ha0;
            pw[3] = hi ? Hb1 : Hb0;
            bf16x8 vf = *(const bf16x8*)(vbase + kt * 32 + 16 * h + 8 * hi);
            acc = __builtin_amdgcn_mfma_f32_32x32x16_bf16(vf, __builtin_bit_cast(bf16x8, pw), acc, 0, 0, 0);
        }
        kf = kfn;
    }

    float inv = 1.0f / acc[4];
    __syncthreads();
    float* sO = (float*)smem;
    int qloc = wv * 32 + l31;
    float4 t0;
    t0.x = acc[0] * inv; t0.y = acc[1] * inv; t0.z = acc[2] * inv; t0.w = acc[3] * inv;
    *(float4*)(sO + qloc * 12 + 4 * hi) = t0;
    __syncthreads();
    float* og = O + (bh * 1024 + chunk * 128) * 8;
    {
        int q = tid >> 1, part = tid & 1;
        *(float4*)(og + tid * 4) = *(const float4*)(sO + q * 12 + part * 4);
    }
}

// ---------------------------------------------------------------- layer tail: X = LN(X + O@Wo); X = LN(X + relu(X@W1+b1)@W2+b2); [aw]
// 64 rows/block, 512 threads, grid 256. The tail is LDS-BANDWIDTH bound (~2.7MB
// LDS reads/block); doubling rows per block with round-18's per-thread tiles
// (proj/ffn2: 2rx4c, ffn1/aw: 4rx4j) halves total LDS traffic per launch and
// amortizes each weight restage over 2x rows. LDS 68.6KB -> 1 block/CU (8 waves).
__global__ __launch_bounds__(512) void tail_kernel(
    float* __restrict__ X, const float* __restrict__ O, const float* __restrict__ Wo,
    const float* __restrict__ W1, const float* __restrict__ b1,
    const float* __restrict__ W2, const float* __restrict__ b2,
    const float* __restrict__ gamma, const float* __restrict__ beta, int gi,
    const float* __restrict__ aW1, const float* __restrict__ ab1,
    const float* __restrict__ aW2, float* __restrict__ aw, int doAw)
{
    __shared__ __align__(16) float sW[128 * 68];         // 34816B (WoT/W1T/W2T/aW1T)
    __shared__ __align__(16) float sX[4096];             // 16384B residual stream [64][64]
    __shared__ __align__(16) unsigned char sHraw[17408]; // O stage [64][68]f32 / hid [64][136]bf16 / out [64][64]f32
    int tid = threadIdx.x;                               // 0..511
    int row0 = blockIdx.x * 64;
    int lane = tid & 63, wave = tid >> 6;                // 8 waves
    float* sHo = (float*)sHraw;
    __bf16* sHb = (__bf16*)sHraw;
    float* sHout = (float*)sHraw;

    // stage WoT [c][68]; O rows gathered (stride 68); X rows
    for (int idx = tid; idx < 4096; idx += 512) {
        int j = idx >> 6, c = idx & 63;
        sW[c * 68 + j] = Wo[idx];
    }
#pragma unroll
    for (int it = 0; it < 8; ++it) {
        int idx = it * 512 + tid;           // r*64 + j, r in 0..63
        int r = idx >> 6, j = idx & 63;
        int grow = row0 + r;
        int b = grow >> 10, l = grow & 1023;
        int bh = b * 8 + (j >> 3);
        sHo[r * 68 + j] = O[(bh * 1024 + l) * 8 + (j & 7)];
    }
#pragma unroll
    for (int it = 0; it < 2; ++it)
        ((float4*)sX)[it * 512 + tid] = ((const float4*)(X + row0 * 64))[it * 512 + tid];
    __syncthreads();

    // proj GEMM: 2 rows x 4 cols per thread (32 row-pairs x 16 col-groups = 512)
    {
        int c4 = tid & 15, r0b = (tid >> 4) * 2;   // r0b in 0..62
        float acc[2][4] = {{0.f,0.f,0.f,0.f},{0.f,0.f,0.f,0.f}};
#pragma unroll 2
        for (int j = 0; j < 64; j += 4) {
            float4 hv0 = *(const float4*)(sHo + r0b * 68 + j);
            float4 hv1 = *(const float4*)(sHo + (r0b + 1) * 68 + j);
#pragma unroll
            for (int cc = 0; cc < 4; ++cc) {
                float4 wv = *(const float4*)(sW + (c4 + 16 * cc) * 68 + j);
                acc[0][cc] = fmaf(hv0.x, wv.x, acc[0][cc]); acc[0][cc] = fmaf(hv0.y, wv.y, acc[0][cc]);
                acc[0][cc] = fmaf(hv0.z, wv.z, acc[0][cc]); acc[0][cc] = fmaf(hv0.w, wv.w, acc[0][cc]);
                acc[1][cc] = fmaf(hv1.x, wv.x, acc[1][cc]); acc[1][cc] = fmaf(hv1.y, wv.y, acc[1][cc]);
                acc[1][cc] = fmaf(hv1.z, wv.z, acc[1][cc]); acc[1][cc] = fmaf(hv1.w, wv.w, acc[1][cc]);
            }
        }
#pragma unroll
        for (int rr = 0; rr < 2; ++rr)
#pragma unroll
            for (int cc = 0; cc < 4; ++cc)
                sX[(r0b + rr) * 64 + c4 + 16 * cc] += acc[rr][cc];
    }
    __syncthreads();
    // LN1 (gamma[gi]): 8 waves x 8 rows
#pragma unroll
    for (int it = 0; it < 8; ++it) {
        int r = wave * 8 + it;
        float x = sX[r * 64 + lane];
        float mean = wave_sum64(x) * (1.0f / 64.0f);
        float dx = x - mean;
        float var = wave_sum64(dx * dx) * (1.0f / 64.0f);
        sX[r * 64 + lane] = dx * rsqrtf(var + 1e-14f) * gamma[gi] + beta[gi];
    }
    __syncthreads();

    // restage W1T [j][68]
    for (int idx = tid; idx < 8192; idx += 512) {
        int c = idx >> 7, j = idx & 127;
        sW[j * 68 + c] = W1[idx];
    }
    __syncthreads();
    // ffn1: hid = relu(sX@W1+b1) -> sHb[64][136] bf16; 4 rows x 4 j per thread
    {
        int j4 = tid & 31;
        int r0 = (tid >> 5) * 4;            // 0..60
        float acc[4][4];
#pragma unroll
        for (int jj = 0; jj < 4; ++jj) {
            float bb = b1[j4 + 32 * jj];
#pragma unroll
            for (int rr = 0; rr < 4; ++rr) acc[rr][jj] = bb;
        }
#pragma unroll 2
        for (int c = 0; c < 64; c += 4) {
            float4 xv[4];
#pragma unroll
            for (int rr = 0; rr < 4; ++rr) xv[rr] = *(const float4*)(sX + (r0 + rr) * 64 + c);
#pragma unroll
            for (int jj = 0; jj < 4; ++jj) {
                float4 wv = *(const float4*)(sW + (j4 + 32 * jj) * 68 + c);
#pragma unroll
                for (int rr = 0; rr < 4; ++rr) {
                    acc[rr][jj] = fmaf(xv[rr].x, wv.x, acc[rr][jj]);
                    acc[rr][jj] = fmaf(xv[rr].y, wv.y, acc[rr][jj]);
                    acc[rr][jj] = fmaf(xv[rr].z, wv.z, acc[rr][jj]);
                    acc[rr][jj] = fmaf(xv[rr].w, wv.w, acc[rr][jj]);
                }
            }
        }
#pragma unroll
        for (int rr = 0; rr < 4; ++rr)
#pragma unroll
            for (int jj = 0; jj < 4; ++jj)
                sHb[(r0 + rr) * 136 + j4 + 32 * jj] = (__bf16)fmaxf(acc[rr][jj], 0.0f);
    }
    __syncthreads();
    // restage W2T [c][132]
    for (int idx = tid; idx < 8192; idx += 512) {
        int j = idx >> 6, c = idx & 63;
        sW[c * 132 + j] = W2[idx];
    }
    __syncthreads();
    // ffn2: out = hid@W2+b2; 2 rows x 4 cols per thread
    int c4 = tid & 15;
    int r0b = (tid >> 4) * 2;               // 0..62
    float acc2[2][4];
#pragma unroll
    for (int cc = 0; cc < 4; ++cc) {
        float bb = b2[c4 + 16 * cc];
        acc2[0][cc] = bb; acc2[1][cc] = bb;
    }
#pragma unroll 2
    for (int jc = 0; jc < 128; jc += 8) {
        float hf[2][8];
#pragma unroll
        for (int rr = 0; rr < 2; ++rr) {
            bf16x8 hb = *(const bf16x8*)(sHb + (r0b + rr) * 136 + jc);
#pragma unroll
            for (int e = 0; e < 8; ++e) hf[rr][e] = b2f(hb[e]);
        }
#pragma unroll
        for (int cc = 0; cc < 4; ++cc) {
            float4 w0 = *(const float4*)(sW + (c4 + 16 * cc) * 132 + jc);
            float4 w1 = *(const float4*)(sW + (c4 + 16 * cc) * 132 + jc + 4);
#pragma unroll
            for (int rr = 0; rr < 2; ++rr) {
                acc2[rr][cc] = fmaf(hf[rr][0], w0.x, acc2[rr][cc]);
                acc2[rr][cc] = fmaf(hf[rr][1], w0.y, acc2[rr][cc]);
                acc2[rr][cc] = fmaf(hf[rr][2], w0.z, acc2[rr][cc]);
                acc2[rr][cc] = fmaf(hf[rr][3], w0.w, acc2[rr][cc]);
                acc2[rr][cc] = fmaf(hf[rr][4], w1.x, acc2[rr][cc]);
                acc2[rr][cc] = fmaf(hf[rr][5], w1.y, acc2[rr][cc]);
                acc2[rr][cc] = fmaf(hf[rr][6], w1.z, acc2[rr][cc]);
                acc2[rr][cc] = fmaf(hf[rr][7], w1.w, acc2[rr][cc]);
            }
        }
    }
    __syncthreads();           // hid reads done; reuse sHraw as f32 out buffer
#pragma unroll
    for (int rr = 0; rr < 2; ++rr)
#pragma unroll
        for (int cc = 0; cc < 4; ++cc)
            sHout[(r0b + rr) * 64 + c4 + 16 * cc] = acc2[rr][cc];
    __syncthreads();
    // LN2 (gamma[gi+1]); write X global (and sX if aw follows)
#pragma unroll
    for (int it = 0; it < 8; ++it) {
        int r = wave * 8 + it;
        float x = sX[r * 64 + lane] + sHout[r * 64 + lane];
        float mean = wave_sum64(x) * (1.0f / 64.0f);
        float dx = x - mean;
        float var = wave_sum64(dx * dx) * (1.0f / 64.0f);
        float xo = dx * rsqrtf(var + 1e-14f) * gamma[gi + 1] + beta[gi + 1];
        X[(row0 + r) * 64 + lane] = xo;
        if (doAw) sX[r * 64 + lane] = xo;
    }
    if (!doAw) return;

    // aw phase: restage aW1T [j][68], GEMM + tanh*aW2 + row reduce; 4 rows per thread
    __syncthreads();
    for (int idx = tid; idx < 8192; idx += 512) {
        int c = idx >> 7, j = idx & 127;
        sW[j * 68 + c] = aW1[idx];
    }
    __syncthreads();
    {
        int j4 = tid & 31;
        int r0 = (tid >> 5) * 4;
        float acc[4][4];
#pragma unroll
        for (int jj = 0; jj < 4; ++jj) {
            float bb = ab1[j4 + 32 * jj];
#pragma unroll
            for (int rr = 0; rr < 4; ++rr) acc[rr][jj] = bb;
        }
#pragma unroll 2
        for (int c = 0; c < 64; c += 4) {
            float4 xv[4];
#pragma unroll
            for (int rr = 0; rr < 4; ++rr) xv[rr] = *(const float4*)(sX + (r0 + rr) * 64 + c);
#pragma unroll
            for (int jj = 0; jj < 4; ++jj) {
                float4 wv = *(const float4*)(sW + (j4 + 32 * jj) * 68 + c);
#pragma unroll
                for (int rr = 0; rr < 4; ++rr) {
                    acc[rr][jj] = fmaf(xv[rr].x, wv.x, acc[rr][jj]);
                    acc[rr][jj] = fmaf(xv[rr].y, wv.y, acc[rr][jj]);
                    acc[rr][jj] = fmaf(xv[rr].z, wv.z, acc[rr][jj]);
                    acc[rr][jj] = fmaf(xv[rr].w, wv.w, acc[rr][jj]);
                }
            }
        }
        float a2[4];
#pragma unroll
        for (int jj = 0; jj < 4; ++jj) a2[jj] = aW2[j4 + 32 * jj];
#pragma unroll
        for (int rr = 0; rr < 4; ++rr) {
            float part = tanhf(acc[rr][0]) * a2[0] + tanhf(acc[rr][1]) * a2[1]
                       + tanhf(acc[rr][2]) * a2[2] + tanhf(acc[rr][3]) * a2[3];
#pragma unroll
            for (int off = 16; off > 0; off >>= 1) part += __shfl_xor(part, off, 64);
            if ((lane & 31) == 0) aw[row0 + r0 + rr] = part;
        }
    }
}

// ---------------------------------------------------------------- fused pool: stats + weighted sum + head
__global__ __launch_bounds__(1024) void pool_kernel(
    const float* __restrict__ X, const float* __restrict__ aw, const float* __restrict__ mask,
    const float* __restrict__ denc, const float* __restrict__ Wout,
    const float* __restrict__ bout, float* __restrict__ out)
{
    __shared__ float sp[1024];
    __shared__ float red[16];
    __shared__ float red2[16];
    __shared__ float sf[16][64];
    int b = blockIdx.x, tid = threadIdx.x;
    float s = (mask[b * 1024 + tid] != 0.0f) ? aw[b * 1024 + tid] : -1e30f;
    float m = s;
#pragma unroll
    for (int off = 32; off > 0; off >>= 1) m = fmaxf(m, __shfl_xor(m, off, 64));
    if ((tid & 63) == 0) red[tid >> 6] = m;
    __syncthreads();
    float gmax = red[0];
#pragma unroll
    for (int i = 1; i < 16; ++i) gmax = fmaxf(gmax, red[i]);
    float p = __expf(s - gmax);
    sp[tid] = p;
    float psum = wave_sum64(p);
    if ((tid & 63) == 0) red2[tid >> 6] = psum;
    __syncthreads();
    float tot = 0.f;
#pragma unroll
    for (int i = 0; i < 16; ++i) tot += red2[i];
    float inv = 1.0f / tot;
    int c = tid & 63, g = tid >> 6;
    int l0 = g * 64;
    float f = 0.f;
#pragma unroll 4
    for (int i = 0; i < 64; ++i)
        f = fmaf(sp[l0 + i], X[(b * 1024 + l0 + i) * 64 + c], f);
    sf[g][c] = f;
    __syncthreads();
    if (tid < 64) {
        float fc = 0.f;
#pragma unroll
        for (int ch = 0; ch < 16; ++ch) fc += sf[ch][tid];
        fc *= inv;
        float contrib = fc * Wout[tid] + denc[b * 64 + tid] * Wout[64 + tid];
        contrib = wave_sum64(contrib);
        if (tid == 0) out[b] = 1.0f / (1.0f + __expf(-(contrib + bout[0])));
    }
}

// ---------------------------------------------------------------- launch
extern "C" void kernel_launch(void* const* d_in, const int* in_sizes, int n_in,
                              void* d_out, int out_size, void* d_ws, size_t ws_size,
                              hipStream_t stream)
{
    const float* demo  = (const float*)d_in[0];
    const float* times = (const float*)d_in[1];
    const float* values= (const float*)d_in[2];
    const int*   varis = (const int*)d_in[3];
    const float* emb   = (const float*)d_in[4];
    const float* vW1   = (const float*)d_in[5];
    const float* vb1   = (const float*)d_in[6];
    const float* vW2   = (const float*)d_in[7];
    const float* tW1   = (const float*)d_in[8];
    const float* tb1   = (const float*)d_in[9];
    const float* tW2   = (const float*)d_in[10];
    const float* Wq    = (const float*)d_in[11];
    const float* Wk    = (const float*)d_in[12];
    const float* Wv    = (const float*)d_in[13];
    const float* Wo    = (const float*)d_in[14];
    const float* W1    = (const float*)d_in[15];
    const float* b1    = (const float*)d_in[16];
    const float* W2    = (const float*)d_in[17];
    const float* b2    = (const float*)d_in[18];
    const float* gamma = (const float*)d_in[19];
    const float* beta  = (const float*)d_in[20];
    const float* aW1   = (const float*)d_in[21];
    const float* ab1   = (const float*)d_in[22];
    const float* aW2   = (const float*)d_in[23];
    const float* dW1   = (const float*)d_in[24];
    const float* db1   = (const float*)d_in[25];
    const float* dW2   = (const float*)d_in[26];
    const float* db2   = (const float*)d_in[27];
    const float* Wout  = (const float*)d_in[28];
    const float* bout  = (const float*)d_in[29];
    float* out = (float*)d_out;

    float* ws     = (float*)d_ws;
    float* X      = ws;                        // 1048576 f
    float* mask   = X + 1048576;               // 16384 f
    __bf16* qbf   = (__bf16*)(mask + 16384);   // 1048576 bf16 (524288 f)
    __bf16* kbf   = qbf + 1048576;             // 1048576 bf16
    __bf16* vtb   = kbf + 1048576;             // 1048576 bf16
    float* Ob     = (float*)(vtb + 1048576);   // 1048576 f
    float* awb    = Ob + 1048576;              // 16384 f
    float* denc   = awb + 16384;               // 1024 f

    embed_demo_kernel<<<4112, 256, 0, stream>>>(times, values, varis, emb, vW1, vb1, vW2,
                                                tW1, tb1, tW2, demo, dW1, db1, dW2, db2,
                                                X, mask, denc);
    for (int i = 0; i < 2; ++i) {
        qkv_kernel<<<1024, 256, 0, stream>>>(X, mask, Wq + i * 4096, Wk + i * 4096, Wv + i * 4096,
                                             qbf, kbf, vtb);
        attn_mfma_kernel<<<1024, 256, 0, stream>>>(qbf, kbf, vtb, Ob);
        tail_kernel<<<256, 512, 0, stream>>>(X, Ob, Wo + i * 4096,
                                             W1 + i * 8192, b1 + i * 128, W2 + i * 8192, b2 + i * 64,
                                             gamma, beta, 2 * i,
                                             aW1, ab1, aW2, awb, (i == 1) ? 1 : 0);
    }
    pool_kernel<<<16, 1024, 0, stream>>>(X, awb, mask, denc, Wout, bout, out);
}

// Round 22
// 158.360 us; speedup vs baseline: 1.0303x; 1.0303x over previous
//
#include <hip/hip_runtime.h>
#include <math.h>

// Sizes (fixed): B=16, L=1024, D=50, V=129, d=64, N=2, H=8, DK=8, DFF=128, CVE=8
// LN eps = 1e-14, MASK_ATTN = -1e-30 (~zero!), MASK_POOL = -1e30.

typedef __bf16 bf16x8 __attribute__((ext_vector_type(8)));
typedef __bf16 bf16x2 __attribute__((ext_vector_type(2)));
typedef float f32x16 __attribute__((ext_vector_type(16)));
typedef unsigned int uint4e __attribute__((ext_vector_type(4)));
typedef unsigned long long u64;

static __device__ __forceinline__ float wave_sum64(float x) {
#pragma unroll
    for (int off = 32; off > 0; off >>= 1) x += __shfl_xor(x, off, 64);
    return x;
}

static __device__ __forceinline__ unsigned pack2(float a, float b) {
    bf16x2 t; t[0] = (__bf16)a; t[1] = (__bf16)b;
    return __builtin_bit_cast(unsigned, t);
}

static __device__ __forceinline__ float b2f(__bf16 h) {   // exact bf16 -> f32
    unsigned short us = __builtin_bit_cast(unsigned short, h);
    unsigned u = ((unsigned)us) << 16;
    return __builtin_bit_cast(float, u);
}

static __device__ __forceinline__ float exp2fast(float x) {
#if defined(__has_builtin) && __has_builtin(__builtin_amdgcn_exp2f)
    return __builtin_amdgcn_exp2f(x);
#else
    return exp2f(x);
#endif
}

// lo <- value held by the hi=0 lane of the (lane, lane^32) pair; hi_ <- hi=1 lane's value.
static __device__ __forceinline__ void plswap(unsigned v, unsigned& lo, unsigned& hi_) {
#if defined(__has_builtin) && __has_builtin(__builtin_amdgcn_permlane32_swap)
    auto r = __builtin_amdgcn_permlane32_swap(v, v, false, false);
    lo = r[0]; hi_ = r[1];
#else
    unsigned x = __shfl_xor(v, 32, 64);
    bool h = (threadIdx.x & 32) != 0;
    lo = h ? x : v;
    hi_ = h ? v : x;
#endif
}

// ---------------------------------------------------------------- embeddings + demo (merged)
__global__ __launch_bounds__(256) void embed_demo_kernel(
    const float* __restrict__ times, const float* __restrict__ values,
    const int* __restrict__ varis, const float* __restrict__ emb,
    const float* __restrict__ vW1, const float* __restrict__ vb1, const float* __restrict__ vW2,
    const float* __restrict__ tW1, const float* __restrict__ tb1, const float* __restrict__ tW2,
    const float* __restrict__ demo, const float* __restrict__ dW1, const float* __restrict__ db1,
    const float* __restrict__ dW2, const float* __restrict__ db2,
    float* __restrict__ X, float* __restrict__ mask, float* __restrict__ denc)
{
    __shared__ float sh[128];
    int tid = threadIdx.x;
    if (blockIdx.x < 4096) {
        int row = blockIdx.x * 4 + (tid >> 6);  // (b*L + l)
        int c   = tid & 63;
        float v = values[row];
        float t = times[row];
        int var = varis[row];
        if (c == 0) mask[row] = (var > 0) ? 1.0f : 0.0f;
        float th = 0.f;
        if (c < 8)       th = tanhf(fmaf(v, vW1[c], vb1[c]));
        else if (c < 16) th = tanhf(fmaf(t, tW1[c - 8], tb1[c - 8]));
        float acc = emb[var * 64 + c];
#pragma unroll
        for (int j = 0; j < 8; ++j) {
            acc = fmaf(__shfl(th, j, 64),     vW2[j * 64 + c], acc);
            acc = fmaf(__shfl(th, j + 8, 64), tW2[j * 64 + c], acc);
        }
        X[row * 64 + c] = acc;
    } else {
        int b = blockIdx.x - 4096;
        if (tid < 128) {
            float a = db1[tid];
            for (int j = 0; j < 50; ++j) a = fmaf(demo[b * 50 + j], dW1[j * 128 + tid], a);
            sh[tid] = tanhf(a);
        }
        __syncthreads();
        if (tid < 64) {
            float a2 = db2[tid];
#pragma unroll 8
            for (int j = 0; j < 128; ++j) a2 = fmaf(sh[j], dW2[j * 64 + tid], a2);
            denc[b * 64 + tid] = tanhf(a2);
        }
    }
}

// ---------------------------------------------------------------- qkv projection
__global__ __launch_bounds__(256) void qkv_kernel(
    const float* __restrict__ X, const float* __restrict__ mask,
    const float* __restrict__ Wq, const float* __restrict__ Wk, const float* __restrict__ Wv,
    __bf16* __restrict__ qbf, __bf16* __restrict__ kbf, __bf16* __restrict__ vtb)
{
    __shared__ __align__(16) unsigned char qsm[52224];  // 3 x [64][68] f32
    float* sWq = (float*)qsm;
    float* sWk = sWq + 4352;
    float* sWv = sWk + 4352;
    int tid = threadIdx.x;
    for (int idx = tid; idx < 4096; idx += 256) {
        int h = idx >> 9, c = (idx >> 3) & 63, kk = idx & 7;
        int o = h * 8 + kk;
        sWq[o * 68 + c] = Wq[idx];
        sWk[o * 68 + c] = Wk[idx];
        sWv[o * 68 + c] = Wv[idx];
    }
    int row0 = blockIdx.x * 16;
    __syncthreads();
    int lane = tid & 63;
    int wv4 = (tid >> 6) * 4;                // rows wv4..wv4+3
    float aq[4] = {0.f, 0.f, 0.f, 0.f};
    float ak[4] = {0.f, 0.f, 0.f, 0.f};
    float av[4] = {0.f, 0.f, 0.f, 0.f};
#pragma unroll
    for (int c = 0; c < 64; c += 4) {
        float4 xv[4];
#pragma unroll
        for (int rr = 0; rr < 4; ++rr)
            xv[rr] = *(const float4*)(X + (row0 + wv4 + rr) * 64 + c);  // wave-broadcast
        float4 wq = *(const float4*)(sWq + lane * 68 + c);
        float4 wk = *(const float4*)(sWk + lane * 68 + c);
        float4 wvv= *(const float4*)(sWv + lane * 68 + c);
#pragma unroll
        for (int rr = 0; rr < 4; ++rr) {
            aq[rr] = fmaf(xv[rr].x, wq.x, aq[rr]);  aq[rr] = fmaf(xv[rr].y, wq.y, aq[rr]);
            aq[rr] = fmaf(xv[rr].z, wq.z, aq[rr]);  aq[rr] = fmaf(xv[rr].w, wq.w, aq[rr]);
            ak[rr] = fmaf(xv[rr].x, wk.x, ak[rr]);  ak[rr] = fmaf(xv[rr].y, wk.y, ak[rr]);
            ak[rr] = fmaf(xv[rr].z, wk.z, ak[rr]);  ak[rr] = fmaf(xv[rr].w, wk.w, ak[rr]);
            av[rr] = fmaf(xv[rr].x, wvv.x, av[rr]); av[rr] = fmaf(xv[rr].y, wvv.y, av[rr]);
            av[rr] = fmaf(xv[rr].z, wvv.z, av[rr]); av[rr] = fmaf(xv[rr].w, wvv.w, av[rr]);
        }
    }
    float aqr[4], akr[4], avr[4];
#pragma unroll
    for (int rr = 0; rr < 4; ++rr) {
        float km = mask[row0 + wv4 + rr];   // wave-uniform broadcast
        aqr[rr] = aq[rr] * 1.4426950408889634f;
        akr[rr] = (km != 0.f) ? ak[rr] : 0.f;
        avr[rr] = av[rr];
    }
    __syncthreads();   // weights no longer needed; reuse LDS for repack
    __bf16* sQb = (__bf16*)qsm;
    __bf16* sKb = (__bf16*)(qsm + 2304);
    __bf16* sVt = (__bf16*)(qsm + 4608);   // [64][18]
    int h = lane >> 3, kk = lane & 7;
#pragma unroll
    for (int rr = 0; rr < 4; ++rr) {
        int r = wv4 + rr;
        sQb[h * 136 + r * 8 + kk] = (__bf16)aqr[rr];
        sKb[h * 136 + r * 8 + kk] = (__bf16)akr[rr];
        sVt[lane * 18 + r] = (__bf16)avr[rr];
    }
    __syncthreads();
    int b = row0 >> 10, l0 = row0 & 1023;
    unsigned* qg = (unsigned*)qbf;
    unsigned* kg = (unsigned*)kbf;
    const unsigned* q32 = (const unsigned*)sQb;
    const unsigned* k32 = (const unsigned*)sKb;
#pragma unroll
    for (int it = 0; it < 2; ++it) {
        int idx = it * 256 + tid;            // 0..511
        int hh = idx >> 6, w = idx & 63;     // per h: 64 u32 = 256B dense
        int gbase = ((b * 8 + hh) * 1024 + l0) * 4;
        qg[gbase + w] = q32[hh * 68 + w];
        kg[gbase + w] = k32[hh * 68 + w];
    }
#pragma unroll
    for (int it = 0; it < 2; ++it) {
        int idx = it * 256 + tid;            // 0..511 -> (hkk, lpair)
        int hkk = idx >> 3, lp = idx & 7;
        unsigned w = ((const unsigned*)sVt)[hkk * 9 + lp];
        int hh = hkk >> 3, k2 = hkk & 7;
        ((unsigned*)(vtb + (b * 8 + hh) * 8192 + k2 * 1024 + l0))[lp] = w;
    }
}

// ---------------------------------------------------------------- MFMA attention (NO split-K)
// ONE q-group per wave (~60 live VGPRs, no spill). Grid 1024 = 8 chunks x 128 bh.
__global__ __launch_bounds__(256, 2) void attn_mfma_kernel(
    const __bf16* __restrict__ qbf, const __bf16* __restrict__ kbf,
    const __bf16* __restrict__ vtb, float* __restrict__ O)
{
    __shared__ __align__(16) unsigned char smem[35008];
    __bf16* sK  = (__bf16*)smem;             // [1024 keys][8] = 16384B
    __bf16* sVT = (__bf16*)(smem + 16384);   // rows 0..7 V^T (stride 1032), row 8 ones

    int tid   = threadIdx.x;
    int bh    = blockIdx.x & 127;
    int chunk = blockIdx.x >> 7;             // 0..7

    const u64* kg = (const u64*)(kbf + bh * 8192);
    u64* sKq = (u64*)sK;
#pragma unroll
    for (int i = 0; i < 8; ++i) sKq[i * 256 + tid] = kg[i * 256 + tid];

    const u64* vgb = (const u64*)(vtb + bh * 8192);
#pragma unroll
    for (int it = 0; it < 8; ++it) {
        int idx = it * 256 + tid;
        int r = idx >> 8, w = idx & 255;
        ((u64*)(sVT + r * 1032))[w] = vgb[idx];
    }
    {
        unsigned* p1 = (unsigned*)(sVT + 8 * 1032);
        p1[tid] = 0x3f803f80u;
        p1[256 + tid] = 0x3f803f80u;
    }
    __syncthreads();

    int lane = tid & 63;
    int wv   = tid >> 6;
    int hi   = lane >> 5;
    int l31  = lane & 31;
    unsigned hm = hi ? 0u : 0xffffffffu;

    int qrow = chunk * 128 + wv * 32 + l31;

    bf16x8 qf;
    {
        const __bf16* qp = qbf + (bh * 1024 + qrow) * 8;
        uint4e qa = *(const uint4e*)qp;
        qa[0] &= hm; qa[1] &= hm; qa[2] &= hm; qa[3] &= hm;
        qf = __builtin_bit_cast(bf16x8, qa);
    }

    f32x16 acc, zc;
#pragma unroll
    for (int i = 0; i < 16; ++i) { acc[i] = 0.f; zc[i] = 0.f; }

    const bf16x8* sKv = (const bf16x8*)sK;
    const __bf16* vbase = sVT + (l31 < 8 ? l31 : 8) * 1032;

    bf16x8 kf = sKv[l31];
#pragma unroll 2
    for (int kt = 0; kt < 32; ++kt) {
        bf16x8 kfn = sKv[((kt + 1) & 31) * 32 + l31];
        f32x16 st = __builtin_amdgcn_mfma_f32_32x32x16_bf16(kf, qf, zc, 0, 0, 0);
        float p[16];
#pragma unroll
        for (int r = 0; r < 16; ++r) p[r] = exp2fast(st[r]);

#pragma unroll
        for (int h = 0; h < 2; ++h) {
            unsigned La0, Ha0, Lb0, Hb0, La1, Ha1, Lb1, Hb1;
            int g0 = 2 * h, g1 = 2 * h + 1;
            plswap(pack2(p[4 * g0 + 0], p[4 * g0 + 1]), La0, Ha0);
            plswap(pack2(p[4 * g0 + 2], p[4 * g0 + 3]), Lb0, Hb0);
            plswap(pack2(p[4 * g1 + 0], p[4 * g1 + 1]), La1, Ha1);
            plswap(pack2(p[4 * g1 + 2], p[4 * g1 + 3]), Lb1, Hb1);
            uint4e pw;
            pw[0] = hi ? La1 : La0;
            pw[1] = hi ? Lb1 : Lb0;
            pw[2] = hi ? Ha1 : Ha0;
            pw[3] = hi ? Hb1 : Hb0;
            bf16x8 vf = *(const bf16x8*)(vbase + kt * 32 + 16 * h + 8 * hi);
            acc = __builtin_amdgcn_mfma_f32_32x32x16_bf16(vf, __builtin_bit_cast(bf16x8, pw), acc, 0, 0, 0);
        }
        kf = kfn;
    }

    float inv = 1.0f / acc[4];
    __syncthreads();
    float* sO = (float*)smem;
    int qloc = wv * 32 + l31;
    float4 t0;
    t0.x = acc[0] * inv; t0.y = acc[1] * inv; t0.z = acc[2] * inv; t0.w = acc[3] * inv;
    *(float4*)(sO + qloc * 12 + 4 * hi) = t0;
    __syncthreads();
    float* og = O + (bh * 1024 + chunk * 128) * 8;
    {
        int q = tid >> 1, part = tid & 1;
        *(float4*)(og + tid * 4) = *(const float4*)(sO + q * 12 + part * 4);
    }
}

// ---------------------------------------------------------------- layer tail: X = LN(X + O@Wo); X = LN(X + relu(X@W1+b1)@W2+b2); [aw]
// ROUND-20 GEOMETRY (best measured: 32 rows/block, 512 threads, grid 512, 2 blocks/CU
// = 16 waves/CU — the tail is latency-chain bound; 16 waves beat 12 and 8).
// NEW: each weight restage's 16 global loads/thread are PREFETCHED into registers one
// phase early (they pipeline with the prior phase's loads; the pre-barrier vmcnt drain
// completes them under compute), so restages become pure LDS writes. W1-write merged
// into the LN1 phase (disjoint LDS regions).
__global__ __launch_bounds__(512) void tail_kernel(
    float* __restrict__ X, const float* __restrict__ O, const float* __restrict__ Wo,
    const float* __restrict__ W1, const float* __restrict__ b1,
    const float* __restrict__ W2, const float* __restrict__ b2,
    const float* __restrict__ gamma, const float* __restrict__ beta, int gi,
    const float* __restrict__ aW1, const float* __restrict__ ab1,
    const float* __restrict__ aW2, float* __restrict__ aw, int doAw)
{
    __shared__ __align__(16) float sW[128 * 68];        // 34816B (WoT/W1T/W2T/aW1T)
    __shared__ __align__(16) float sX[2048];            // 8192B residual stream
    __shared__ __align__(16) unsigned char sHraw[8704]; // O stage (f32 str 68) / hid bf16 / out f32
    int tid = threadIdx.x;                              // 0..511
    int row0 = blockIdx.x * 32;
    int lane = tid & 63, wave = tid >> 6;               // 8 waves
    float* sHo = (float*)sHraw;
    __bf16* sHb = (__bf16*)sHraw;
    float* sHout = (float*)sHraw;

    // stage WoT [c][68]; O rows (stride 68); X rows; PREFETCH W1 into regs
    for (int idx = tid; idx < 4096; idx += 512) {
        int j = idx >> 6, c = idx & 63;
        sW[c * 68 + j] = Wo[idx];
    }
#pragma unroll
    for (int it = 0; it < 4; ++it) {
        int idx = it * 512 + tid;           // r*64 + j
        int r = idx >> 6, j = idx & 63;
        int grow = row0 + r;
        int b = grow >> 10, l = grow & 1023;
        int bh = b * 8 + (j >> 3);
        sHo[r * 68 + j] = O[(bh * 1024 + l) * 8 + (j & 7)];
    }
    ((float4*)sX)[tid] = ((const float4*)(X + row0 * 64))[tid];
    float w1r[16];
#pragma unroll
    for (int it = 0; it < 16; ++it) w1r[it] = W1[it * 512 + tid];
    __syncthreads();

    // proj GEMM: 1 row x 4 cols per thread
    {
        int c4 = tid & 15, r = tid >> 4;    // r in 0..31
        float acc[4] = {0.f, 0.f, 0.f, 0.f};
#pragma unroll 2
        for (int j = 0; j < 64; j += 4) {
            float4 hv = *(const float4*)(sHo + r * 68 + j);
#pragma unroll
            for (int cc = 0; cc < 4; ++cc) {
                float4 wv = *(const float4*)(sW + (c4 + 16 * cc) * 68 + j);
                acc[cc] = fmaf(hv.x, wv.x, acc[cc]); acc[cc] = fmaf(hv.y, wv.y, acc[cc]);
                acc[cc] = fmaf(hv.z, wv.z, acc[cc]); acc[cc] = fmaf(hv.w, wv.w, acc[cc]);
            }
        }
#pragma unroll
        for (int cc = 0; cc < 4; ++cc)
            sX[r * 64 + c4 + 16 * cc] += acc[cc];
    }
    __syncthreads();
    // LN1 (gamma[gi]) + write W1T from regs (disjoint LDS regions; sW reads ended above)
#pragma unroll
    for (int it = 0; it < 16; ++it) {
        int idx = it * 512 + tid;
        int c = idx >> 7, j = idx & 127;
        sW[j * 68 + c] = w1r[it];
    }
#pragma unroll
    for (int it = 0; it < 4; ++it) {
        int r = wave * 4 + it;
        float x = sX[r * 64 + lane];
        float mean = wave_sum64(x) * (1.0f / 64.0f);
        float dx = x - mean;
        float var = wave_sum64(dx * dx) * (1.0f / 64.0f);
        sX[r * 64 + lane] = dx * rsqrtf(var + 1e-14f) * gamma[gi] + beta[gi];
    }
    // PREFETCH W2 into regs
    float w2r[16];
#pragma unroll
    for (int it = 0; it < 16; ++it) w2r[it] = W2[it * 512 + tid];
    __syncthreads();

    // ffn1: hid = relu(sX@W1+b1) -> sHb[32][136] bf16; 2 rows x 4 j per thread
    {
        int j4 = tid & 31;
        int r0 = (tid >> 5) * 2;            // 0..30
        float acc[2][4];
#pragma unroll
        for (int jj = 0; jj < 4; ++jj) {
            float bb = b1[j4 + 32 * jj];
            acc[0][jj] = bb; acc[1][jj] = bb;
        }
#pragma unroll 2
        for (int c = 0; c < 64; c += 4) {
            float4 xv0 = *(const float4*)(sX + r0 * 64 + c);
            float4 xv1 = *(const float4*)(sX + (r0 + 1) * 64 + c);
#pragma unroll
            for (int jj = 0; jj < 4; ++jj) {
                float4 wv = *(const float4*)(sW + (j4 + 32 * jj) * 68 + c);
                acc[0][jj] = fmaf(xv0.x, wv.x, acc[0][jj]); acc[0][jj] = fmaf(xv0.y, wv.y, acc[0][jj]);
                acc[0][jj] = fmaf(xv0.z, wv.z, acc[0][jj]); acc[0][jj] = fmaf(xv0.w, wv.w, acc[0][jj]);
                acc[1][jj] = fmaf(xv1.x, wv.x, acc[1][jj]); acc[1][jj] = fmaf(xv1.y, wv.y, acc[1][jj]);
                acc[1][jj] = fmaf(xv1.z, wv.z, acc[1][jj]); acc[1][jj] = fmaf(xv1.w, wv.w, acc[1][jj]);
            }
        }
#pragma unroll
        for (int rr = 0; rr < 2; ++rr)
#pragma unroll
            for (int jj = 0; jj < 4; ++jj)
                sHb[(r0 + rr) * 136 + j4 + 32 * jj] = (__bf16)fmaxf(acc[rr][jj], 0.0f);
    }
    __syncthreads();
    // write W2T from regs; PREFETCH aW1 if needed
#pragma unroll
    for (int it = 0; it < 16; ++it) {
        int idx = it * 512 + tid;
        int j = idx >> 6, c = idx & 63;
        sW[c * 132 + j] = w2r[it];
    }
    float a1r[16];
    if (doAw) {
#pragma unroll
        for (int it = 0; it < 16; ++it) a1r[it] = aW1[it * 512 + tid];
    }
    __syncthreads();

    // ffn2: out = hid@W2+b2; 1 row x 4 cols per thread
    int c4 = tid & 15;
    int rrow = tid >> 4;                    // 0..31
    float acc2[4];
#pragma unroll
    for (int cc = 0; cc < 4; ++cc) acc2[cc] = b2[c4 + 16 * cc];
#pragma unroll 2
    for (int jc = 0; jc < 128; jc += 8) {
        float hf[8];
        bf16x8 hb = *(const bf16x8*)(sHb + rrow * 136 + jc);
#pragma unroll
        for (int e = 0; e < 8; ++e) hf[e] = b2f(hb[e]);
#pragma unroll
        for (int cc = 0; cc < 4; ++cc) {
            float4 w0 = *(const float4*)(sW + (c4 + 16 * cc) * 132 + jc);
            float4 w1 = *(const float4*)(sW + (c4 + 16 * cc) * 132 + jc + 4);
            acc2[cc] = fmaf(hf[0], w0.x, acc2[cc]); acc2[cc] = fmaf(hf[1], w0.y, acc2[cc]);
            acc2[cc] = fmaf(hf[2], w0.z, acc2[cc]); acc2[cc] = fmaf(hf[3], w0.w, acc2[cc]);
            acc2[cc] = fmaf(hf[4], w1.x, acc2[cc]); acc2[cc] = fmaf(hf[5], w1.y, acc2[cc]);
            acc2[cc] = fmaf(hf[6], w1.z, acc2[cc]); acc2[cc] = fmaf(hf[7], w1.w, acc2[cc]);
        }
    }
    __syncthreads();           // hid reads done; reuse sHraw as f32 out buffer
#pragma unroll
    for (int cc = 0; cc < 4; ++cc)
        sHout[rrow * 64 + c4 + 16 * cc] = acc2[cc];
    __syncthreads();
    // LN2 (gamma[gi+1]); write X global (and sX if aw follows)
#pragma unroll
    for (int it = 0; it < 4; ++it) {
        int r = wave * 4 + it;
        float x = sX[r * 64 + lane] + sHout[r * 64 + lane];
        float mean = wave_sum64(x) * (1.0f / 64.0f);
        float dx = x - mean;
        float var = wave_sum64(dx * dx) * (1.0f / 64.0f);
        float xo = dx * rsqrtf(var + 1e-14f) * gamma[gi + 1] + beta[gi + 1];
        X[(row0 + r) * 64 + lane] = xo;
        if (doAw) sX[r * 64 + lane] = xo;
    }
    if (!doAw) return;

    // aw phase: write aW1T from regs, GEMM + tanh*aW2 + row reduce; 2 rows per group
    __syncthreads();
#pragma unroll
    for (int it = 0; it < 16; ++it) {
        int idx = it * 512 + tid;
        int c = idx >> 7, j = idx & 127;
        sW[j * 68 + c] = a1r[it];
    }
    __syncthreads();
    {
        int j4 = tid & 31;
        int r0 = (tid >> 5) * 2;
        float acc[2][4];
#pragma unroll
        for (int jj = 0; jj < 4; ++jj) {
            float bb = ab1[j4 + 32 * jj];
            acc[0][jj] = bb; acc[1][jj] = bb;
        }
#pragma unroll 2
        for (int c = 0; c < 64; c += 4) {
            float4 xv0 = *(const float4*)(sX + r0 * 64 + c);
            float4 xv1 = *(const float4*)(sX + (r0 + 1) * 64 + c);
#pragma unroll
            for (int jj = 0; jj < 4; ++jj) {
                float4 wv = *(const float4*)(sW + (j4 + 32 * jj) * 68 + c);
                acc[0][jj] = fmaf(xv0.x, wv.x, acc[0][jj]); acc[0][jj] = fmaf(xv0.y, wv.y, acc[0][jj]);
                acc[0][jj] = fmaf(xv0.z, wv.z, acc[0][jj]); acc[0][jj] = fmaf(xv0.w, wv.w, acc[0][jj]);
                acc[1][jj] = fmaf(xv1.x, wv.x, acc[1][jj]); acc[1][jj] = fmaf(xv1.y, wv.y, acc[1][jj]);
                acc[1][jj] = fmaf(xv1.z, wv.z, acc[1][jj]); acc[1][jj] = fmaf(xv1.w, wv.w, acc[1][jj]);
            }
        }
        float a2[4];
#pragma unroll
        for (int jj = 0; jj < 4; ++jj) a2[jj] = aW2[j4 + 32 * jj];
#pragma unroll
        for (int rr = 0; rr < 2; ++rr) {
            float part = tanhf(acc[rr][0]) * a2[0] + tanhf(acc[rr][1]) * a2[1]
                       + tanhf(acc[rr][2]) * a2[2] + tanhf(acc[rr][3]) * a2[3];
#pragma unroll
            for (int off = 16; off > 0; off >>= 1) part += __shfl_xor(part, off, 64);
            if ((lane & 31) == 0) aw[row0 + r0 + rr] = part;
        }
    }
}

// ---------------------------------------------------------------- fused pool: stats + weighted sum + head
__global__ __launch_bounds__(1024) void pool_kernel(
    const float* __restrict__ X, const float* __restrict__ aw, const float* __restrict__ mask,
    const float* __restrict__ denc, const float* __restrict__ Wout,
    const float* __restrict__ bout, float* __restrict__ out)
{
    __shared__ float sp[1024];
    __shared__ float red[16];
    __shared__ float red2[16];
    __shared__ float sf[16][64];
    int b = blockIdx.x, tid = threadIdx.x;
    float s = (mask[b * 1024 + tid] != 0.0f) ? aw[b * 1024 + tid] : -1e30f;
    float m = s;
#pragma unroll
    for (int off = 32; off > 0; off >>= 1) m = fmaxf(m, __shfl_xor(m, off, 64));
    if ((tid & 63) == 0) red[tid >> 6] = m;
    __syncthreads();
    float gmax = red[0];
#pragma unroll
    for (int i = 1; i < 16; ++i) gmax = fmaxf(gmax, red[i]);
    float p = __expf(s - gmax);
    sp[tid] = p;
    float psum = wave_sum64(p);
    if ((tid & 63) == 0) red2[tid >> 6] = psum;
    __syncthreads();
    float tot = 0.f;
#pragma unroll
    for (int i = 0; i < 16; ++i) tot += red2[i];
    float inv = 1.0f / tot;
    int c = tid & 63, g = tid >> 6;
    int l0 = g * 64;
    float f = 0.f;
#pragma unroll 4
    for (int i = 0; i < 64; ++i)
        f = fmaf(sp[l0 + i], X[(b * 1024 + l0 + i) * 64 + c], f);
    sf[g][c] = f;
    __syncthreads();
    if (tid < 64) {
        float fc = 0.f;
#pragma unroll
        for (int ch = 0; ch < 16; ++ch) fc += sf[ch][tid];
        fc *= inv;
        float contrib = fc * Wout[tid] + denc[b * 64 + tid] * Wout[64 + tid];
        contrib = wave_sum64(contrib);
        if (tid == 0) out[b] = 1.0f / (1.0f + __expf(-(contrib + bout[0])));
    }
}

// ---------------------------------------------------------------- launch
extern "C" void kernel_launch(void* const* d_in, const int* in_sizes, int n_in,
                              void* d_out, int out_size, void* d_ws, size_t ws_size,
                              hipStream_t stream)
{
    const float* demo  = (const float*)d_in[0];
    const float* times = (const float*)d_in[1];
    const float* values= (const float*)d_in[2];
    const int*   varis = (const int*)d_in[3];
    const float* emb   = (const float*)d_in[4];
    const float* vW1   = (const float*)d_in[5];
    const float* vb1   = (const float*)d_in[6];
    const float* vW2   = (const float*)d_in[7];
    const float* tW1   = (const float*)d_in[8];
    const float* tb1   = (const float*)d_in[9];
    const float* tW2   = (const float*)d_in[10];
    const float* Wq    = (const float*)d_in[11];
    const float* Wk    = (const float*)d_in[12];
    const float* Wv    = (const float*)d_in[13];
    const float* Wo    = (const float*)d_in[14];
    const float* W1    = (const float*)d_in[15];
    const float* b1    = (const float*)d_in[16];
    const float* W2    = (const float*)d_in[17];
    const float* b2    = (const float*)d_in[18];
    const float* gamma = (const float*)d_in[19];
    const float* beta  = (const float*)d_in[20];
    const float* aW1   = (const float*)d_in[21];
    const float* ab1   = (const float*)d_in[22];
    const float* aW2   = (const float*)d_in[23];
    const float* dW1   = (const float*)d_in[24];
    const float* db1   = (const float*)d_in[25];
    const float* dW2   = (const float*)d_in[26];
    const float* db2   = (const float*)d_in[27];
    const float* Wout  = (const float*)d_in[28];
    const float* bout  = (const float*)d_in[29];
    float* out = (float*)d_out;

    float* ws     = (float*)d_ws;
    float* X      = ws;                        // 1048576 f
    float* mask   = X + 1048576;               // 16384 f
    __bf16* qbf   = (__bf16*)(mask + 16384);   // 1048576 bf16 (524288 f)
    __bf16* kbf   = qbf + 1048576;             // 1048576 bf16
    __bf16* vtb   = kbf + 1048576;             // 1048576 bf16
    float* Ob     = (float*)(vtb + 1048576);   // 1048576 f
    float* awb    = Ob + 1048576;              // 16384 f
    float* denc   = awb + 16384;               // 1024 f

    embed_demo_kernel<<<4112, 256, 0, stream>>>(times, values, varis, emb, vW1, vb1, vW2,
                                                tW1, tb1, tW2, demo, dW1, db1, dW2, db2,
                                                X, mask, denc);
    for (int i = 0; i < 2; ++i) {
        qkv_kernel<<<1024, 256, 0, stream>>>(X, mask, Wq + i * 4096, Wk + i * 4096, Wv + i * 4096,
                                             qbf, kbf, vtb);
        attn_mfma_kernel<<<1024, 256, 0, stream>>>(qbf, kbf, vtb, Ob);
        tail_kernel<<<512, 512, 0, stream>>>(X, Ob, Wo + i * 4096,
                                             W1 + i * 8192, b1 + i * 128, W2 + i * 8192, b2 + i * 64,
                                             gamma, beta, 2 * i,
                                             aW1, ab1, aW2, awb, (i == 1) ? 1 : 0);
    }
    pool_kernel<<<16, 1024, 0, stream>>>(X, awb, mask, denc, Wout, bout, out);
}